// Round 22
// baseline (85.606 us; speedup 1.0000x reference)
//
#include <hip/hip_runtime.h>
#include <math.h>

#define BATCH 4
#define CH    96
#define HH    48
#define WW    48
#define HWPIX (HH*WW)         // 2304
#define NPIX  (BATCH*HWPIX)   // 9216
#define WIN   13
#define WIN2  169
#define HALF  6
#define TOPK  8
#define NEGV  (-1000000000.0f)

// ---------------------------------------------------------------------------
// K0: transpose weights once: w1 [192][96] -> w1T [96][192],
//     w2 [96][192] -> w2T [192][96]. 36 blocks x 256 thr. (passing)
// ---------------------------------------------------------------------------
__global__ __launch_bounds__(256) void k0_wt(
    const float* __restrict__ w1, const float* __restrict__ w2,
    float* __restrict__ w1T, float* __restrict__ w2T)
{
    __shared__ float tile[32][33];
    int bid = blockIdx.x;          // 0..17: w1 (6x3 tiles), 18..35: w2 (3x6)
    const float* src; float* dst; int R, C, tr, tc;
    if (bid < 18) { src = w1; dst = w1T; R = 192; C = 96;  tr = bid / 3; tc = bid % 3; }
    else { int b2 = bid - 18; src = w2; dst = w2T; R = 96; C = 192; tr = b2 / 6; tc = b2 % 6; }
    int r0 = tr * 32, c0 = tc * 32;
    int tx = threadIdx.x & 31, ty = threadIdx.x >> 5;   // ty 0..7

    #pragma unroll
    for (int i = 0; i < 4; ++i) {
        int r = ty + i * 8;
        tile[r][tx] = src[(r0 + r) * C + c0 + tx];
    }
    __syncthreads();
    #pragma unroll
    for (int i = 0; i < 4; ++i) {
        int r = ty + i * 8;
        dst[(c0 + r) * R + r0 + tx] = tile[tx][r];   // dst[c][r] = src[r][c]
    }
}

// ---------------------------------------------------------------------------
// K1: x (B,C,H,W) -> xt2 CHUNK-MAJOR [(c/4)][pixel] float4 cells (in ws now),
//     + per-pixel invn / mu / rstd. 576 blocks x 256 thr, 16 px/block.
// ---------------------------------------------------------------------------
__global__ __launch_bounds__(256) void k1_prep(
    const float* __restrict__ x, float* __restrict__ xt2,
    float* __restrict__ invn, float* __restrict__ muv, float* __restrict__ rsd)
{
    __shared__ float lds[96][17];
    int bid = blockIdx.x;          // 576 = 4 batches * 144 tiles
    int b   = bid / 144;
    int p0  = (bid % 144) * 16;
    int t   = threadIdx.x;

    #pragma unroll
    for (int it = 0; it < 6; ++it) {
        int e = t + it * 256;      // 1536 = 96c * 16px
        int c = e >> 4;
        int p = e & 15;
        lds[c][p] = x[(b * CH + c) * HWPIX + p0 + p];
    }
    __syncthreads();

    if (t < 16) {
        float s = 0.f, ss = 0.f;
        #pragma unroll
        for (int c = 0; c < CH; ++c) { float v = lds[c][t]; s += v; ss += v * v; }
        int gpix = b * HWPIX + p0 + t;
        invn[gpix] = 1.0f / fmaxf(sqrtf(ss), 1e-12f);
        float m = s * (1.0f / 96.0f);
        muv[gpix] = m;
        rsd[gpix] = rsqrtf(ss * (1.0f / 96.0f) - m * m + 1e-5f);
    }

    // chunk-major write: 384 float4 cells (16 px * 24 chunks)
    float4* x4 = (float4*)xt2;
    for (int i = t; i < 384; i += 256) {
        int p = i & 15;
        int s = i >> 4;            // chunk 0..23
        float4 v = make_float4(lds[4*s][p], lds[4*s+1][p],
                               lds[4*s+2][p], lds[4*s+3][p]);
        x4[s * NPIX + b * HWPIX + p0 + p] = v;
    }
}

// ---------------------------------------------------------------------------
// K2: FUSED KNN + LayerNorm + FFN. 2304 blocks x 256 thr, 4 px/block
//     (1 wave = 1 pixel for the KNN part, proven geometry).
//     Phase 1 (per wave): chunk-major dots, ballot top-8, softmax, gather,
//                         LayerNorm -> enh_l in LDS (no global enh).
//     Phase A (t<192): thread = hidden j, 4 px; weights lane-consecutive,
//                      activations via LDS uniform broadcast. -> hl
//     Phase B (t<96):  thread = channel c, 4 px; h via LDS broadcast;
//                      out written as ONE float4 spanning 4 pixels.
//     FFN loads overlap other waves' dot phases (k3 latency absorbed).
// ---------------------------------------------------------------------------
__global__ __launch_bounds__(256) void k2_fused(
    const float* __restrict__ xt2, const float* __restrict__ invn,
    const float* __restrict__ muv, const float* __restrict__ rsd,
    const float* __restrict__ lnw, const float* __restrict__ lnb,
    const float* __restrict__ w1T, const float* __restrict__ b1,
    const float* __restrict__ w2T, const float* __restrict__ b2,
    float* __restrict__ out)
{
    __shared__ float own[4][96];
    __shared__ float enh_l[4][100];   // pad -> wave-staggered banks
    __shared__ float hl[4][200];
    int t    = threadIdx.x;
    int wv   = t >> 6;
    int lane = t & 63;
    int gp   = blockIdx.x * 4 + wv;
    int b    = gp / HWPIX;
    int p    = gp - b * HWPIX;
    int py   = p / WW;
    int px   = p - py * WW;
    const float4* x4 = (const float4*)xt2;

    // ---- phase 1: KNN + LN (per wave, one pixel) ----
    float4 ownv = make_float4(0.f, 0.f, 0.f, 0.f);
    if (lane < 24) {
        ownv = x4[lane * NPIX + gp];
        ((float4*)(own[wv]))[lane] = ownv;   // wave-private
    }
    float inp = invn[gp];
    float mu  = muv[gp];
    float rs  = rsd[gp];

    float v0 = -2e9f, v1 = -2e9f, v2 = -2e9f;
    const float4* ov = (const float4*)(own[wv]);
    #pragma unroll
    for (int k = 0; k < 3; ++k) {
        int n = lane + 64 * k;
        float sim = -2e9f;
        if (n < WIN2) {
            int dy = n / WIN - HALF;
            int dx = n - (dy + HALF) * WIN - HALF;
            int ny = py + dy, nx = px + dx;
            if (ny >= 0 && ny < HH && nx >= 0 && nx < WW) {
                int q = b * HWPIX + ny * WW + nx;
                float inq = invn[q];
                const float4* rp = x4 + q;
                float ax = 0.f, ay = 0.f, az = 0.f, aw = 0.f;
                #pragma unroll
                for (int s = 0; s < 24; ++s) {
                    float4 a  = ov[s];
                    float4 bb = rp[s * NPIX];
                    ax += a.x * bb.x; ay += a.y * bb.y;
                    az += a.z * bb.z; aw += a.w * bb.w;
                }
                sim = ((ax + ay) + (az + aw)) * inp * inq;
            } else {
                sim = NEGV;
            }
        }
        if (k == 0) v0 = sim; else if (k == 1) v1 = sim; else v2 = sim;
    }

    float tv[TOPK]; int tn[TOPK];
    #pragma unroll
    for (int r = 0; r < TOPK; ++r) {
        float m = fmaxf(fmaxf(v0, v1), v2);
        #pragma unroll
        for (int off = 1; off < 64; off <<= 1)
            m = fmaxf(m, __shfl_xor(m, off));
        unsigned long long m0 = __ballot(v0 == m);
        unsigned long long m1 = __ballot(v1 == m);
        unsigned long long m2 = __ballot(v2 == m);
        int n;
        if (m0)      n = (int)__builtin_ctzll(m0);
        else if (m1) n = 64 + (int)__builtin_ctzll(m1);
        else         n = 128 + (int)__builtin_ctzll(m2);
        tv[r] = m; tn[r] = n;
        int kk = n >> 6, ll = n & 63;
        if (ll == lane) {
            if (kk == 0)      v0 = -2e9f;
            else if (kk == 1) v1 = -2e9f;
            else              v2 = -2e9f;
        }
    }

    float wts[TOPK]; int qn[TOPK];
    float wsum = 0.f;
    #pragma unroll
    for (int r = 0; r < TOPK; ++r) {
        float e = expf(tv[r] - tv[0]);
        wts[r] = e; wsum += e;
        int n  = tn[r];
        int dy = n / WIN - HALF;
        int dx = n - (dy + HALF) * WIN - HALF;
        int gy = min(max(py + dy, 0), HH - 1);
        int gx = min(max(px + dx, 0), WW - 1);
        qn[r]  = b * HWPIX + gy * WW + gx;
    }
    float winv = 1.0f / wsum;

    if (lane < 24) {
        const float4* base = x4 + lane * NPIX;
        float4 g = make_float4(0.f, 0.f, 0.f, 0.f);
        #pragma unroll
        for (int r = 0; r < TOPK; ++r) {
            float4 f = base[qn[r]];
            float w = wts[r];
            g.x += w * f.x; g.y += w * f.y;
            g.z += w * f.z; g.w += w * f.w;
        }
        float4 lw = ((const float4*)lnw)[lane];
        float4 lb = ((const float4*)lnb)[lane];
        int c0 = lane * 4;
        enh_l[wv][c0 + 0] = g.x * winv + (ownv.x - mu) * rs * lw.x + lb.x;
        enh_l[wv][c0 + 1] = g.y * winv + (ownv.y - mu) * rs * lw.y + lb.y;
        enh_l[wv][c0 + 2] = g.z * winv + (ownv.z - mu) * rs * lw.z + lb.z;
        enh_l[wv][c0 + 3] = g.w * winv + (ownv.w - mu) * rs * lw.w + lb.w;
    }
    __syncthreads();

    // ---- phase A: h = relu(enh @ w1T + b1) for 4 pixels ----
    if (t < 192) {
        int j = t;
        float a0 = 0.f, a1 = 0.f, a2 = 0.f, a3 = 0.f;
        #pragma unroll 6
        for (int c4 = 0; c4 < 24; ++c4) {
            float wa = w1T[(4*c4 + 0) * 192 + j];   // lane-consecutive j
            float wb = w1T[(4*c4 + 1) * 192 + j];
            float wc = w1T[(4*c4 + 2) * 192 + j];
            float wd = w1T[(4*c4 + 3) * 192 + j];
            int cc = 4 * c4;
            float e0a = enh_l[0][cc], e0b = enh_l[0][cc+1], e0c = enh_l[0][cc+2], e0d = enh_l[0][cc+3];
            float e1a = enh_l[1][cc], e1b = enh_l[1][cc+1], e1c = enh_l[1][cc+2], e1d = enh_l[1][cc+3];
            float e2a = enh_l[2][cc], e2b = enh_l[2][cc+1], e2c = enh_l[2][cc+2], e2d = enh_l[2][cc+3];
            float e3a = enh_l[3][cc], e3b = enh_l[3][cc+1], e3c = enh_l[3][cc+2], e3d = enh_l[3][cc+3];
            a0 += e0a*wa + e0b*wb + e0c*wc + e0d*wd;
            a1 += e1a*wa + e1b*wb + e1c*wc + e1d*wd;
            a2 += e2a*wa + e2b*wb + e2c*wc + e2d*wd;
            a3 += e3a*wa + e3b*wb + e3c*wc + e3d*wd;
        }
        float bj = b1[j];
        hl[0][j] = fmaxf(a0 + bj, 0.f);
        hl[1][j] = fmaxf(a1 + bj, 0.f);
        hl[2][j] = fmaxf(a2 + bj, 0.f);
        hl[3][j] = fmaxf(a3 + bj, 0.f);
    }
    __syncthreads();

    // ---- phase B: out = enh + h @ w2T + b2; float4 over 4 pixels ----
    if (t < 96) {
        int c = t;
        float s0 = 0.f, s1 = 0.f, s2 = 0.f, s3 = 0.f;
        #pragma unroll 6
        for (int j4 = 0; j4 < 48; ++j4) {
            float wa = w2T[(4*j4 + 0) * 96 + c];    // lane-consecutive c
            float wb = w2T[(4*j4 + 1) * 96 + c];
            float wc = w2T[(4*j4 + 2) * 96 + c];
            float wd = w2T[(4*j4 + 3) * 96 + c];
            int jj = 4 * j4;
            float h0a = hl[0][jj], h0b = hl[0][jj+1], h0c = hl[0][jj+2], h0d = hl[0][jj+3];
            float h1a = hl[1][jj], h1b = hl[1][jj+1], h1c = hl[1][jj+2], h1d = hl[1][jj+3];
            float h2a = hl[2][jj], h2b = hl[2][jj+1], h2c = hl[2][jj+2], h2d = hl[2][jj+3];
            float h3a = hl[3][jj], h3b = hl[3][jj+1], h3c = hl[3][jj+2], h3d = hl[3][jj+3];
            s0 += h0a*wa + h0b*wb + h0c*wc + h0d*wd;
            s1 += h1a*wa + h1b*wb + h1c*wc + h1d*wd;
            s2 += h2a*wa + h2b*wb + h2c*wc + h2d*wd;
            s3 += h3a*wa + h3b*wb + h3c*wc + h3d*wd;
        }
        float bc = b2[c];
        int gp0 = blockIdx.x * 4;
        int bb  = gp0 / HWPIX;
        int pp0 = gp0 - bb * HWPIX;          // multiple of 4
        float4 o;
        o.x = enh_l[0][c] + s0 + bc;
        o.y = enh_l[1][c] + s1 + bc;
        o.z = enh_l[2][c] + s2 + bc;
        o.w = enh_l[3][c] + s3 + bc;
        *(float4*)(out + (bb * CH + c) * HWPIX + pp0) = o;   // 16B aligned
    }
}

// ---------------------------------------------------------------------------
extern "C" void kernel_launch(void* const* d_in, const int* in_sizes, int n_in,
                              void* d_out, int out_size, void* d_ws, size_t ws_size,
                              hipStream_t stream)
{
    const float* x   = (const float*)d_in[0];
    const float* w1  = (const float*)d_in[1];
    const float* b1  = (const float*)d_in[2];
    const float* w2  = (const float*)d_in[3];
    const float* b2  = (const float*)d_in[4];
    const float* lnw = (const float*)d_in[5];
    const float* lnb = (const float*)d_in[6];
    float* out = (float*)d_out;

    // ws layout: xt2 + invn + muv + rsd + w1T + w2T = 948,480 floats = 3.79 MB
    // (xt2 moved to ws because the fused kernel reads xt2 while writing out).
    float* ws   = (float*)d_ws;
    float* xt2  = ws;                        // NPIX*96 = 884736
    float* invn = xt2 + NPIX * CH;           // NPIX
    float* muv  = invn + NPIX;               // NPIX
    float* rsd  = muv + NPIX;                // NPIX
    float* w1T  = rsd + NPIX;                // 18432
    float* w2T  = w1T + 192 * 96;            // 18432

    hipLaunchKernelGGL(k0_wt, dim3(36), dim3(256), 0, stream,
                       w1, w2, w1T, w2T);
    hipLaunchKernelGGL(k1_prep, dim3(576), dim3(256), 0, stream,
                       x, xt2, invn, muv, rsd);
    hipLaunchKernelGGL(k2_fused, dim3(NPIX / 4), dim3(256), 0, stream,
                       xt2, invn, muv, rsd, lnw, lnb, w1T, b1, w2T, b2, out);
}

// Round 23
// 79.446 us; speedup vs baseline: 1.0775x; 1.0775x over previous
//
#include <hip/hip_runtime.h>
#include <math.h>

#define BATCH 4
#define CH    96
#define HH    48
#define WW    48
#define HWPIX (HH*WW)         // 2304
#define NPIX  (BATCH*HWPIX)   // 9216
#define WIN   13
#define WIN2  169
#define HALF  6
#define TOPK  8
#define NEGV  (-1000000000.0f)

// ---------------------------------------------------------------------------
// K0: transpose weights once: w1 [192][96] -> w1T [96][192],
//     w2 [96][192] -> w2T [192][96]. 36 blocks x 256 thr. (passing)
// ---------------------------------------------------------------------------
__global__ __launch_bounds__(256) void k0_wt(
    const float* __restrict__ w1, const float* __restrict__ w2,
    float* __restrict__ w1T, float* __restrict__ w2T)
{
    __shared__ float tile[32][33];
    int bid = blockIdx.x;          // 0..17: w1 (6x3 tiles), 18..35: w2 (3x6)
    const float* src; float* dst; int R, C, tr, tc;
    if (bid < 18) { src = w1; dst = w1T; R = 192; C = 96;  tr = bid / 3; tc = bid % 3; }
    else { int b2 = bid - 18; src = w2; dst = w2T; R = 96; C = 192; tr = b2 / 6; tc = b2 % 6; }
    int r0 = tr * 32, c0 = tc * 32;
    int tx = threadIdx.x & 31, ty = threadIdx.x >> 5;   // ty 0..7

    #pragma unroll
    for (int i = 0; i < 4; ++i) {
        int r = ty + i * 8;
        tile[r][tx] = src[(r0 + r) * C + c0 + tx];
    }
    __syncthreads();
    #pragma unroll
    for (int i = 0; i < 4; ++i) {
        int r = ty + i * 8;
        dst[(c0 + r) * R + r0 + tx] = tile[tx][r];   // dst[c][r] = src[r][c]
    }
}

// ---------------------------------------------------------------------------
// K1: x (B,C,H,W) -> xt2 CHUNK-MAJOR [(c/4)][pixel] float4 cells (in d_out),
//     + per-pixel invn / mu / rstd. 576 blocks x 256 thr, 16 px/block.
// ---------------------------------------------------------------------------
__global__ __launch_bounds__(256) void k1_prep(
    const float* __restrict__ x, float* __restrict__ xt2,
    float* __restrict__ invn, float* __restrict__ muv, float* __restrict__ rsd)
{
    __shared__ float lds[96][17];
    int bid = blockIdx.x;          // 576 = 4 batches * 144 tiles
    int b   = bid / 144;
    int p0  = (bid % 144) * 16;
    int t   = threadIdx.x;

    #pragma unroll
    for (int it = 0; it < 6; ++it) {
        int e = t + it * 256;      // 1536 = 96c * 16px
        int c = e >> 4;
        int p = e & 15;
        lds[c][p] = x[(b * CH + c) * HWPIX + p0 + p];
    }
    __syncthreads();

    if (t < 16) {
        float s = 0.f, ss = 0.f;
        #pragma unroll
        for (int c = 0; c < CH; ++c) { float v = lds[c][t]; s += v; ss += v * v; }
        int gpix = b * HWPIX + p0 + t;
        invn[gpix] = 1.0f / fmaxf(sqrtf(ss), 1e-12f);
        float m = s * (1.0f / 96.0f);
        muv[gpix] = m;
        rsd[gpix] = rsqrtf(ss * (1.0f / 96.0f) - m * m + 1e-5f);
    }

    // chunk-major write: 384 float4 cells (16 px * 24 chunks)
    float4* x4 = (float4*)xt2;
    for (int i = t; i < 384; i += 256) {
        int p = i & 15;
        int s = i >> 4;            // chunk 0..23
        float4 v = make_float4(lds[4*s][p], lds[4*s+1][p],
                               lds[4*s+2][p], lds[4*s+3][p]);
        x4[s * NPIX + b * HWPIX + p0 + p] = v;
    }
}

// ---------------------------------------------------------------------------
// K2: one pixel per wave, 2304 blocks x 256 thr, chunk-major reads,
//     ballot top-8, LN stats from k1. Identical math to the passing r16-r19
//     version; ONLY change: __launch_bounds__(256, 4) unlocks ~128 VGPRs so
//     the 72 independent dot-phase loads can pipeline (was capped at 52).
// ---------------------------------------------------------------------------
__global__ __launch_bounds__(256, 4) void k2_knn(
    const float* __restrict__ xt2, const float* __restrict__ invn,
    const float* __restrict__ muv, const float* __restrict__ rsd,
    const float* __restrict__ lnw, const float* __restrict__ lnb,
    float* __restrict__ enh)
{
    __shared__ float own[4][96];
    int t    = threadIdx.x;
    int wv   = t >> 6;
    int lane = t & 63;
    int gp   = blockIdx.x * 4 + wv;
    int b    = gp / HWPIX;
    int p    = gp - b * HWPIX;
    int py   = p / WW;
    int px   = p - py * WW;
    const float4* x4 = (const float4*)xt2;

    float4 ownv = make_float4(0.f, 0.f, 0.f, 0.f);
    if (lane < 24) {
        ownv = x4[lane * NPIX + gp];
        ((float4*)(own[wv]))[lane] = ownv;
    }
    float inp = invn[gp];
    float mu  = muv[gp];
    float rs  = rsd[gp];

    float v0 = -2e9f, v1 = -2e9f, v2 = -2e9f;
    const float4* ov = (const float4*)(own[wv]);
    #pragma unroll
    for (int k = 0; k < 3; ++k) {
        int n = lane + 64 * k;
        float sim = -2e9f;
        if (n < WIN2) {
            int dy = n / WIN - HALF;
            int dx = n - (dy + HALF) * WIN - HALF;
            int ny = py + dy, nx = px + dx;
            if (ny >= 0 && ny < HH && nx >= 0 && nx < WW) {
                int q = b * HWPIX + ny * WW + nx;
                float inq = invn[q];
                const float4* rp = x4 + q;
                float ax = 0.f, ay = 0.f, az = 0.f, aw = 0.f;
                #pragma unroll
                for (int s = 0; s < 24; ++s) {
                    float4 a  = ov[s];
                    float4 bb = rp[s * NPIX];
                    ax += a.x * bb.x; ay += a.y * bb.y;
                    az += a.z * bb.z; aw += a.w * bb.w;
                }
                sim = ((ax + ay) + (az + aw)) * inp * inq;
            } else {
                sim = NEGV;
            }
        }
        if (k == 0) v0 = sim; else if (k == 1) v1 = sim; else v2 = sim;
    }

    float tv[TOPK]; int tn[TOPK];
    #pragma unroll
    for (int r = 0; r < TOPK; ++r) {
        float m = fmaxf(fmaxf(v0, v1), v2);
        #pragma unroll
        for (int off = 1; off < 64; off <<= 1)
            m = fmaxf(m, __shfl_xor(m, off));
        unsigned long long m0 = __ballot(v0 == m);
        unsigned long long m1 = __ballot(v1 == m);
        unsigned long long m2 = __ballot(v2 == m);
        int n;
        if (m0)      n = (int)__builtin_ctzll(m0);
        else if (m1) n = 64 + (int)__builtin_ctzll(m1);
        else         n = 128 + (int)__builtin_ctzll(m2);
        tv[r] = m; tn[r] = n;
        int kk = n >> 6, ll = n & 63;
        if (ll == lane) {
            if (kk == 0)      v0 = -2e9f;
            else if (kk == 1) v1 = -2e9f;
            else              v2 = -2e9f;
        }
    }

    float wts[TOPK]; int qn[TOPK];
    float wsum = 0.f;
    #pragma unroll
    for (int r = 0; r < TOPK; ++r) {
        float e = expf(tv[r] - tv[0]);
        wts[r] = e; wsum += e;
        int n  = tn[r];
        int dy = n / WIN - HALF;
        int dx = n - (dy + HALF) * WIN - HALF;
        int gy = min(max(py + dy, 0), HH - 1);
        int gx = min(max(px + dx, 0), WW - 1);
        qn[r]  = b * HWPIX + gy * WW + gx;
    }
    float winv = 1.0f / wsum;

    if (lane < 24) {
        const float4* base = x4 + lane * NPIX;
        float4 g = make_float4(0.f, 0.f, 0.f, 0.f);
        #pragma unroll
        for (int r = 0; r < TOPK; ++r) {
            float4 f = base[qn[r]];
            float w = wts[r];
            g.x += w * f.x; g.y += w * f.y;
            g.z += w * f.z; g.w += w * f.w;
        }
        float4 lw = ((const float4*)lnw)[lane];
        float4 lb = ((const float4*)lnb)[lane];
        float4 e;
        e.x = g.x * winv + (ownv.x - mu) * rs * lw.x + lb.x;
        e.y = g.y * winv + (ownv.y - mu) * rs * lw.y + lb.y;
        e.z = g.z * winv + (ownv.z - mu) * rs * lw.z + lb.z;
        e.w = g.w * winv + (ownv.w - mu) * rs * lw.w + lb.w;
        ((float4*)(enh + gp * CH))[lane] = e;
    }
}

// ---------------------------------------------------------------------------
// K3: fused FFN, weight-amortized: 8 px/block, 1152 blocks x 192 thr.
//     Identical to the passing r19 version; ONLY change:
//     __launch_bounds__(192, 4) unlocks ~128 VGPRs for load pipelining.
// ---------------------------------------------------------------------------
__global__ __launch_bounds__(192, 4) void k3_ffn(
    const float* __restrict__ enh, const float* __restrict__ w1T,
    const float* __restrict__ b1, const float* __restrict__ w2T,
    const float* __restrict__ b2, float* __restrict__ out)
{
    __shared__ float hl[8][200];   // 6.25 KB, 800 B rows
    int g  = blockIdx.x;           // 1152 = 4 batches * 288 tiles
    int b  = g / 288;
    int p0 = (g % 288) * 8;
    int t  = threadIdx.x;
    const float4* ebase = (const float4*)(enh + (b * HWPIX + p0) * CH); // rows @ r*24

    // phase A: one hidden unit j for 8 block-uniform pixels
    {
        int j = t;                 // 0..191
        float a0=0.f,a1=0.f,a2=0.f,a3=0.f,a4=0.f,a5=0.f,a6=0.f,a7=0.f;
        #pragma unroll 4
        for (int c4 = 0; c4 < 24; ++c4) {
            float wa = w1T[(4*c4 + 0) * 192 + j];   // lane-consecutive j
            float wb = w1T[(4*c4 + 1) * 192 + j];
            float wc = w1T[(4*c4 + 2) * 192 + j];
            float wd = w1T[(4*c4 + 3) * 192 + j];
            float4 v0 = ebase[0*24 + c4];           // block-uniform -> s_load
            float4 v1 = ebase[1*24 + c4];
            float4 v2 = ebase[2*24 + c4];
            float4 v3 = ebase[3*24 + c4];
            float4 v4 = ebase[4*24 + c4];
            float4 v5 = ebase[5*24 + c4];
            float4 v6 = ebase[6*24 + c4];
            float4 v7 = ebase[7*24 + c4];
            a0 += v0.x*wa + v0.y*wb + v0.z*wc + v0.w*wd;
            a1 += v1.x*wa + v1.y*wb + v1.z*wc + v1.w*wd;
            a2 += v2.x*wa + v2.y*wb + v2.z*wc + v2.w*wd;
            a3 += v3.x*wa + v3.y*wb + v3.z*wc + v3.w*wd;
            a4 += v4.x*wa + v4.y*wb + v4.z*wc + v4.w*wd;
            a5 += v5.x*wa + v5.y*wb + v5.z*wc + v5.w*wd;
            a6 += v6.x*wa + v6.y*wb + v6.z*wc + v6.w*wd;
            a7 += v7.x*wa + v7.y*wb + v7.z*wc + v7.w*wd;
        }
        float bj = b1[j];
        hl[0][j] = fmaxf(a0 + bj, 0.f);
        hl[1][j] = fmaxf(a1 + bj, 0.f);
        hl[2][j] = fmaxf(a2 + bj, 0.f);
        hl[3][j] = fmaxf(a3 + bj, 0.f);
        hl[4][j] = fmaxf(a4 + bj, 0.f);
        hl[5][j] = fmaxf(a5 + bj, 0.f);
        hl[6][j] = fmaxf(a6 + bj, 0.f);
        hl[7][j] = fmaxf(a7 + bj, 0.f);
    }
    __syncthreads();

    // phase B: c = t%96, half = t/96; 4 pixels (half*4 .. half*4+3)
    {
        int c    = (t >= 96) ? t - 96 : t;
        int half = (t >= 96) ? 1 : 0;
        int q0p  = half * 4;
        const float4* h0 = (const float4*)(&hl[q0p    ][0]);
        const float4* h1 = (const float4*)(&hl[q0p + 1][0]);
        const float4* h2 = (const float4*)(&hl[q0p + 2][0]);
        const float4* h3 = (const float4*)(&hl[q0p + 3][0]);
        float s0 = 0.f, s1 = 0.f, s2 = 0.f, s3 = 0.f;
        #pragma unroll 6
        for (int j4 = 0; j4 < 48; ++j4) {
            float wa = w2T[(4*j4 + 0) * 96 + c];    // lane-consecutive c
            float wb = w2T[(4*j4 + 1) * 96 + c];
            float wc = w2T[(4*j4 + 2) * 96 + c];
            float wd = w2T[(4*j4 + 3) * 96 + c];
            float4 u0 = h0[j4], u1 = h1[j4], u2 = h2[j4], u3 = h3[j4];
            s0 += u0.x*wa + u0.y*wb + u0.z*wc + u0.w*wd;
            s1 += u1.x*wa + u1.y*wb + u1.z*wc + u1.w*wd;
            s2 += u2.x*wa + u2.y*wb + u2.z*wc + u2.w*wd;
            s3 += u3.x*wa + u3.y*wb + u3.z*wc + u3.w*wd;
        }
        float bc = b2[c];
        int pb = p0 + q0p;
        out[(b * CH + c) * HWPIX + pb + 0] =
            enh[(b * HWPIX + pb + 0) * CH + c] + s0 + bc;
        out[(b * CH + c) * HWPIX + pb + 1] =
            enh[(b * HWPIX + pb + 1) * CH + c] + s1 + bc;
        out[(b * CH + c) * HWPIX + pb + 2] =
            enh[(b * HWPIX + pb + 2) * CH + c] + s2 + bc;
        out[(b * CH + c) * HWPIX + pb + 3] =
            enh[(b * HWPIX + pb + 3) * CH + c] + s3 + bc;
    }
}

// ---------------------------------------------------------------------------
extern "C" void kernel_launch(void* const* d_in, const int* in_sizes, int n_in,
                              void* d_out, int out_size, void* d_ws, size_t ws_size,
                              hipStream_t stream)
{
    const float* x   = (const float*)d_in[0];
    const float* w1  = (const float*)d_in[1];
    const float* b1  = (const float*)d_in[2];
    const float* w2  = (const float*)d_in[3];
    const float* b2  = (const float*)d_in[4];
    const float* lnw = (const float*)d_in[5];
    const float* lnb = (const float*)d_in[6];
    float* out = (float*)d_out;

    // xt2 (chunk-major features) lives in d_out: k1 writes, k2 consumes,
    // k3 then overwrites d_out with the final output (stream-ordered).
    float* xt2 = out;

    // workspace: enh + invn + muv + rsd + w1T + w2T = 949,248 floats = 3.80 MB
    float* ws   = (float*)d_ws;
    float* enh  = ws;                        // NPIX*96
    float* invn = enh + NPIX * CH;           // NPIX
    float* muv  = invn + NPIX;               // NPIX
    float* rsd  = muv + NPIX;                // NPIX
    float* w1T  = rsd + NPIX;                // 96*192 = 18432
    float* w2T  = w1T + 192 * 96;            // 192*96 = 18432

    hipLaunchKernelGGL(k0_wt, dim3(36), dim3(256), 0, stream,
                       w1, w2, w1T, w2T);
    hipLaunchKernelGGL(k1_prep, dim3(576), dim3(256), 0, stream,
                       x, xt2, invn, muv, rsd);
    hipLaunchKernelGGL(k2_knn, dim3(NPIX / 4), dim3(256), 0, stream,
                       xt2, invn, muv, rsd, lnw, lnb, enh);
    hipLaunchKernelGGL(k3_ffn, dim3(1152), dim3(192), 0, stream,
                       enh, w1T, b1, w2T, b2, out);
}